// Round 1
// baseline (50.552 us; speedup 1.0000x reference)
//
#include <hip/hip_runtime.h>

// Problem constants (from reference):
//   x: [64, 64, 128, 128] f32, weight: [64, 64, 3, 3] f32, bias: [64] f32
//   out: [64, 64, 1, 1] f32
//   Hout = Wout = 256; masks all-ones except (ih=0,kh=0) and (iw=0,kw=0).
// Algebra:
//   sx[b,c,kh,kw] = T - (kh==0)*R0 - (kw==0)*C0 + (kh==0&&kw==0)*X00
//   acc[b,o] = sum_c [ T*Wsum - R0*Wrow0 - C0*Wcol0 + X00*W00 ]
//   out = (acc/65536 + bias) * 0.5

#define N_PLANES 4096   // B*CIN
#define CIN 64
#define COUT 64
#define PLANE_F4 4096   // 128*128/4 float4 per plane

__global__ __launch_bounds__(256) void plane_reduce(const float* __restrict__ x,
                                                    float4* __restrict__ sx4) {
    const int plane = blockIdx.x;                      // b*CIN + c
    const float4* xp = reinterpret_cast<const float4*>(x) + (size_t)plane * PLANE_F4;
    const int t = threadIdx.x;

    float T = 0.f, R0 = 0.f, C0 = 0.f, X00 = 0.f;
#pragma unroll
    for (int i = 0; i < 16; ++i) {
        const int f = i * 256 + t;                     // float4 index within plane
        const float4 v = xp[f];
        const float s4 = v.x + v.y + v.z + v.w;
        T += s4;
        if (f < 32) R0 += s4;                          // row h=0: first 128 floats
        if ((f & 31) == 0) C0 += v.x;                  // col w=0: every 128th float
        if (f == 0) X00 = v.x;                         // element (0,0): thread 0, i=0
    }

    // wave (64-lane) butterfly reduce
#pragma unroll
    for (int off = 32; off > 0; off >>= 1) {
        T  += __shfl_down(T,  off);
        R0 += __shfl_down(R0, off);
        C0 += __shfl_down(C0, off);
    }

    __shared__ float sT[4], sR[4], sC[4];
    const int wave = t >> 6;
    if ((t & 63) == 0) { sT[wave] = T; sR[wave] = R0; sC[wave] = C0; }
    __syncthreads();
    if (t == 0) {
        sx4[plane] = make_float4(sT[0] + sT[1] + sT[2] + sT[3],
                                 sR[0] + sR[1] + sR[2] + sR[3],
                                 sC[0] + sC[1] + sC[2] + sC[3],
                                 X00);
    }
}

__global__ __launch_bounds__(256) void weight_prep(const float* __restrict__ w,
                                                   float4* __restrict__ w4) {
    const int idx = blockIdx.x * 256 + threadIdx.x;    // c*COUT + o
    if (idx >= CIN * COUT) return;
    const float* wp = w + (size_t)idx * 9;             // weight[c][o][3][3]
    const float a0 = wp[0], a1 = wp[1], a2 = wp[2],
                a3 = wp[3], a4 = wp[4], a5 = wp[5],
                a6 = wp[6], a7 = wp[7], a8 = wp[8];
    const float wsum = a0 + a1 + a2 + a3 + a4 + a5 + a6 + a7 + a8;
    const float wrow = a0 + a1 + a2;                   // kh = 0
    const float wcol = a0 + a3 + a6;                   // kw = 0
    w4[idx] = make_float4(wsum, wrow, wcol, a0);
}

__global__ __launch_bounds__(64) void finalize(const float4* __restrict__ sx4,
                                               const float4* __restrict__ w4,
                                               const float* __restrict__ bias,
                                               float* __restrict__ out) {
    const int b = blockIdx.x;
    const int o = threadIdx.x;

    __shared__ float4 s[CIN];
    s[o] = sx4[b * CIN + o];                           // 64 threads stage 64 planes
    __syncthreads();

    float acc = 0.f;
#pragma unroll 8
    for (int c = 0; c < CIN; ++c) {
        const float4 sv = s[c];
        const float4 wv = w4[c * COUT + o];
        acc += sv.x * wv.x - sv.y * wv.y - sv.z * wv.z + sv.w * wv.w;
    }
    out[b * COUT + o] = (acc * (1.0f / 65536.0f) + bias[o]) * 0.5f;
}

extern "C" void kernel_launch(void* const* d_in, const int* in_sizes, int n_in,
                              void* d_out, int out_size, void* d_ws, size_t ws_size,
                              hipStream_t stream) {
    const float* x    = (const float*)d_in[0];
    const float* w    = (const float*)d_in[1];
    const float* bias = (const float*)d_in[2];
    float* out = (float*)d_out;

    float4* sx4 = (float4*)d_ws;                       // 4096 * 16 B = 64 KiB
    float4* w4  = sx4 + N_PLANES;                      // 4096 * 16 B = 64 KiB

    plane_reduce<<<N_PLANES, 256, 0, stream>>>(x, sx4);
    weight_prep<<<(CIN * COUT + 255) / 256, 256, 0, stream>>>(w, w4);
    finalize<<<64, 64, 0, stream>>>(sx4, w4, bias, out);
}